// Round 1
// baseline (164.356 us; speedup 1.0000x reference)
//
#include <hip/hip_runtime.h>
#include <hip/hip_bf16.h>

#define S_LEN 4096
#define EMB   256
#define NHEAD 8
#define HDIM  32
#define WIN   64
#define BATCH 2

// ---------------- GEMM: C[M,N] = A[M,K] * W[N,K]^T, K = 256 ----------------
#define BM 64
#define BN 64
#define BK 32

__global__ __launch_bounds__(256) void qkv_proj_kernel(
    const float* __restrict__ X,    // [8192, 256]
    const float* __restrict__ W,    // [768, 256]
    const float* __restrict__ bias, // [768]
    float* __restrict__ Qb, float* __restrict__ Kb, float* __restrict__ Vb)
{
    __shared__ __align__(16) float As[BK][BM + 4]; // stride 68 floats = 272B (16B aligned)
    __shared__ __align__(16) float Bs[BK][BN + 4];
    const int tid = threadIdx.x;
    const int tx = tid & 15, ty = tid >> 4;
    const int m0 = blockIdx.y * BM;
    const int n0 = blockIdx.x * BN;
    float acc[4][4] = {};
    for (int k0 = 0; k0 < EMB; k0 += BK) {
#pragma unroll
        for (int r = 0; r < 2; ++r) {
            const int idx = tid + r * 256;
            const int row = idx >> 3, c4 = idx & 7;
            const float4 av = *(const float4*)(X + (size_t)(m0 + row) * EMB + k0 + c4 * 4);
            const float4 bv = *(const float4*)(W + (size_t)(n0 + row) * EMB + k0 + c4 * 4);
            As[c4 * 4 + 0][row] = av.x; As[c4 * 4 + 1][row] = av.y;
            As[c4 * 4 + 2][row] = av.z; As[c4 * 4 + 3][row] = av.w;
            Bs[c4 * 4 + 0][row] = bv.x; Bs[c4 * 4 + 1][row] = bv.y;
            Bs[c4 * 4 + 2][row] = bv.z; Bs[c4 * 4 + 3][row] = bv.w;
        }
        __syncthreads();
#pragma unroll
        for (int kk = 0; kk < BK; ++kk) {
            const float4 a = *(const float4*)&As[kk][ty * 4];
            const float4 b = *(const float4*)&Bs[kk][tx * 4];
            const float ar[4] = {a.x, a.y, a.z, a.w};
            const float br[4] = {b.x, b.y, b.z, b.w};
#pragma unroll
            for (int i = 0; i < 4; ++i)
#pragma unroll
                for (int j = 0; j < 4; ++j)
                    acc[i][j] = fmaf(ar[i], br[j], acc[i][j]);
        }
        __syncthreads();
    }
    const float scale = 0.17677669529663687f; // 1/sqrt(32)
#pragma unroll
    for (int i = 0; i < 4; ++i) {
        const int m = m0 + ty * 4 + i;
        const int b = m >> 12, s = m & (S_LEN - 1);
#pragma unroll
        for (int j = 0; j < 4; ++j) {
            const int f = n0 + tx * 4 + j;
            const float v = acc[i][j] + bias[f];
            const int which = f >> 8;
            const int e = f & 255;
            const int h = e >> 5, d = e & 31;
            const size_t off = (((size_t)b * NHEAD + h) * S_LEN + s) * HDIM + d;
            if (which == 0)      Qb[off] = v * scale;
            else if (which == 1) Kb[off] = v;
            else                 Vb[off] = v;
        }
    }
}

__global__ __launch_bounds__(256) void out_proj_kernel(
    const float* __restrict__ A,    // [8192, 256] attn out
    const float* __restrict__ W,    // [256, 256]
    const float* __restrict__ bias, // [256]
    float* __restrict__ C)          // [8192, 256]
{
    __shared__ __align__(16) float As[BK][BM + 4];
    __shared__ __align__(16) float Bs[BK][BN + 4];
    const int tid = threadIdx.x;
    const int tx = tid & 15, ty = tid >> 4;
    const int m0 = blockIdx.y * BM;
    const int n0 = blockIdx.x * BN;
    float acc[4][4] = {};
    for (int k0 = 0; k0 < EMB; k0 += BK) {
#pragma unroll
        for (int r = 0; r < 2; ++r) {
            const int idx = tid + r * 256;
            const int row = idx >> 3, c4 = idx & 7;
            const float4 av = *(const float4*)(A + (size_t)(m0 + row) * EMB + k0 + c4 * 4);
            const float4 bv = *(const float4*)(W + (size_t)(n0 + row) * EMB + k0 + c4 * 4);
            As[c4 * 4 + 0][row] = av.x; As[c4 * 4 + 1][row] = av.y;
            As[c4 * 4 + 2][row] = av.z; As[c4 * 4 + 3][row] = av.w;
            Bs[c4 * 4 + 0][row] = bv.x; Bs[c4 * 4 + 1][row] = bv.y;
            Bs[c4 * 4 + 2][row] = bv.z; Bs[c4 * 4 + 3][row] = bv.w;
        }
        __syncthreads();
#pragma unroll
        for (int kk = 0; kk < BK; ++kk) {
            const float4 a = *(const float4*)&As[kk][ty * 4];
            const float4 b = *(const float4*)&Bs[kk][tx * 4];
            const float ar[4] = {a.x, a.y, a.z, a.w};
            const float br[4] = {b.x, b.y, b.z, b.w};
#pragma unroll
            for (int i = 0; i < 4; ++i)
#pragma unroll
                for (int j = 0; j < 4; ++j)
                    acc[i][j] = fmaf(ar[i], br[j], acc[i][j]);
        }
        __syncthreads();
    }
    const int f0 = n0 + tx * 4;
    const float b0 = bias[f0 + 0], b1 = bias[f0 + 1], b2 = bias[f0 + 2], b3 = bias[f0 + 3];
#pragma unroll
    for (int i = 0; i < 4; ++i) {
        const int m = m0 + ty * 4 + i;
        float4 st;
        st.x = acc[i][0] + b0; st.y = acc[i][1] + b1;
        st.z = acc[i][2] + b2; st.w = acc[i][3] + b3;
        *(float4*)(C + (size_t)m * EMB + f0) = st;
    }
}

// ---------------- Banded attention: 64 queries/block, 4 lanes/query ----------------
#define KPAD 36  // row stride in floats: 144B, keeps float4 alignment, breaks bank collisions

__global__ __launch_bounds__(256) void local_attn_kernel(
    const float* __restrict__ Qb, const float* __restrict__ Kb,
    const float* __restrict__ Vb, float* __restrict__ Ab)
{
    __shared__ __align__(16) float Ks[192 * KPAD];
    __shared__ __align__(16) float Vs[192 * KPAD];
    const int tid = threadIdx.x;
    const int qt = blockIdx.x;
    const int h  = blockIdx.y;
    const int b  = blockIdx.z;
    const int q0 = qt * 64;
    const int jmin = max(0, q0 - WIN);
    const int jmax = min(S_LEN - 1, q0 + 63 + WIN);
    const int nk = jmax - jmin + 1;           // <= 192
    const size_t bhS = ((size_t)b * NHEAD + h) * S_LEN;
    const float* Kg = Kb + (bhS + jmin) * HDIM;
    const float* Vg = Vb + (bhS + jmin) * HDIM;
    for (int idx = tid; idx < nk * 8; idx += 256) {
        const int row = idx >> 3, c = idx & 7;
        *(float4*)&Ks[row * KPAD + c * 4] = *(const float4*)&Kg[row * HDIM + c * 4];
        *(float4*)&Vs[row * KPAD + c * 4] = *(const float4*)&Vg[row * HDIM + c * 4];
    }
    const int qi = tid >> 2, sub = tid & 3;   // 4 consecutive lanes per query
    const int q = q0 + qi;
    float4 qv[8];
    const float* Qg = Qb + (bhS + q) * HDIM;  // Q pre-scaled by 1/sqrt(D)
#pragma unroll
    for (int c = 0; c < 8; ++c) qv[c] = *(const float4*)(Qg + c * 4);
    __syncthreads();

    const int klo = max(0, q - WIN);
    const int khi = min(S_LEN - 1, q + WIN);
    const int cnt = khi - klo + 1;            // <= 129
    const int rbase = klo - jmin;
    const int nkm1 = nk - 1;

    float e[33];
    float mx = -1e30f;
#pragma unroll
    for (int i = 0; i < 33; ++i) {
        const int t = sub + 4 * i;
        const int row = min(rbase + t, nkm1); // clamp keeps loads in valid data
        const float* kr = &Ks[row * KPAD];
        float s = 0.f;
#pragma unroll
        for (int c = 0; c < 8; ++c) {
            const float4 kv = *(const float4*)(kr + c * 4);
            s = fmaf(qv[c].x, kv.x, s);
            s = fmaf(qv[c].y, kv.y, s);
            s = fmaf(qv[c].z, kv.z, s);
            s = fmaf(qv[c].w, kv.w, s);
        }
        s = (t < cnt) ? s : -1e30f;
        e[i] = s;
        mx = fmaxf(mx, s);
    }
    mx = fmaxf(mx, __shfl_xor(mx, 1));
    mx = fmaxf(mx, __shfl_xor(mx, 2));
    float l = 0.f;
#pragma unroll
    for (int i = 0; i < 33; ++i) {
        const float ee = __expf(e[i] - mx);   // masked entries -> exp(-1e30) == 0
        e[i] = ee;
        l += ee;
    }
    l += __shfl_xor(l, 1);
    l += __shfl_xor(l, 2);

    float o[32];
#pragma unroll
    for (int d = 0; d < 32; ++d) o[d] = 0.f;
#pragma unroll
    for (int i = 0; i < 33; ++i) {
        const int t = sub + 4 * i;
        const int row = min(rbase + t, nkm1);
        const float* vr = &Vs[row * KPAD];
        const float ee = e[i];
#pragma unroll
        for (int c = 0; c < 8; ++c) {
            const float4 vv = *(const float4*)(vr + c * 4);
            o[c * 4 + 0] = fmaf(ee, vv.x, o[c * 4 + 0]);
            o[c * 4 + 1] = fmaf(ee, vv.y, o[c * 4 + 1]);
            o[c * 4 + 2] = fmaf(ee, vv.z, o[c * 4 + 2]);
            o[c * 4 + 3] = fmaf(ee, vv.w, o[c * 4 + 3]);
        }
    }
#pragma unroll
    for (int d = 0; d < 32; ++d) {
        o[d] += __shfl_xor(o[d], 1);
        o[d] += __shfl_xor(o[d], 2);
    }
    const float rl = 1.f / l;
    // lane `sub` writes dims [sub*8, sub*8+8); select with static indices (no scratch)
    float w[8];
#pragma unroll
    for (int u = 0; u < 8; ++u) {
        const float v0 = o[u], v1 = o[8 + u], v2 = o[16 + u], v3 = o[24 + u];
        const float lo = (sub & 1) ? v1 : v0;
        const float hi = (sub & 1) ? v3 : v2;
        w[u] = ((sub & 2) ? hi : lo) * rl;
    }
    float* og = Ab + ((size_t)b * S_LEN + q) * EMB + h * HDIM + sub * 8;
    float4 w0, w1;
    w0.x = w[0]; w0.y = w[1]; w0.z = w[2]; w0.w = w[3];
    w1.x = w[4]; w1.y = w[5]; w1.z = w[6]; w1.w = w[7];
    *(float4*)og = w0;
    *(float4*)(og + 4) = w1;
}

extern "C" void kernel_launch(void* const* d_in, const int* in_sizes, int n_in,
                              void* d_out, int out_size, void* d_ws, size_t ws_size,
                              hipStream_t stream) {
    const float* x  = (const float*)d_in[0];
    const float* wi = (const float*)d_in[1];
    const float* bi = (const float*)d_in[2];
    const float* wo = (const float*)d_in[3];
    const float* bo = (const float*)d_in[4];
    float* out = (float*)d_out;

    const size_t per = (size_t)BATCH * NHEAD * S_LEN * HDIM; // 2,097,152 floats
    float* Qb = (float*)d_ws;
    float* Kb = Qb + per;
    float* Vb = Kb + per;
    float* Ab = Vb + per; // [B, S, E] attention output

    qkv_proj_kernel<<<dim3(12, 128), 256, 0, stream>>>(x, wi, bi, Qb, Kb, Vb);
    local_attn_kernel<<<dim3(S_LEN / 64, NHEAD, BATCH), 256, 0, stream>>>(Qb, Kb, Vb, Ab);
    out_proj_kernel<<<dim3(4, 128), 256, 0, stream>>>(Ab, wo, bo, out);
}

// Round 2
// 157.104 us; speedup vs baseline: 1.0462x; 1.0462x over previous
//
#include <hip/hip_runtime.h>
#include <hip/hip_bf16.h>

#define S_LEN 4096
#define EMB   256
#define NHEAD 8
#define HDIM  32
#define WIN   64
#define BATCH 2

// ================= QKV GEMM: C[8192,768] = X[8192,256] * W[768,256]^T =================
// BM=128, BN=64, BK=32; 256 threads; per-thread 8m x 4n; reg-prefetch pipeline.
#define QBM 128
#define QBN 64
#define QBK 32

__global__ __launch_bounds__(256) void qkv_proj_kernel(
    const float* __restrict__ X, const float* __restrict__ W,
    const float* __restrict__ bias,
    float* __restrict__ Qb, float* __restrict__ Kb, float* __restrict__ Vb)
{
    __shared__ __align__(16) float As[QBK][QBM + 4]; // [32][132], k-major (transposed)
    __shared__ __align__(16) float Bs[QBK][QBN + 4]; // [32][68]
    const int tid = threadIdx.x;
    const int tx = tid & 15, ty = tid >> 4;   // tx: 4n each, ty: 8m each
    const int m0 = blockIdx.y * QBM;
    const int n0 = blockIdx.x * QBN;
    const int arow = tid >> 3, ac4 = tid & 7; // staging: row base, float4-col

    float4 ar[4], br[2];
    // prefetch tile 0
#pragma unroll
    for (int r = 0; r < 4; ++r)
        ar[r] = *(const float4*)(X + (size_t)(m0 + arow + r * 32) * EMB + ac4 * 4);
#pragma unroll
    for (int r = 0; r < 2; ++r)
        br[r] = *(const float4*)(W + (size_t)(n0 + arow + r * 32) * EMB + ac4 * 4);

    float acc[8][4] = {};
    for (int t = 0; t < 8; ++t) {
        __syncthreads(); // previous compute done before overwrite
#pragma unroll
        for (int r = 0; r < 4; ++r) {
            As[ac4 * 4 + 0][arow + r * 32] = ar[r].x;
            As[ac4 * 4 + 1][arow + r * 32] = ar[r].y;
            As[ac4 * 4 + 2][arow + r * 32] = ar[r].z;
            As[ac4 * 4 + 3][arow + r * 32] = ar[r].w;
        }
#pragma unroll
        for (int r = 0; r < 2; ++r) {
            Bs[ac4 * 4 + 0][arow + r * 32] = br[r].x;
            Bs[ac4 * 4 + 1][arow + r * 32] = br[r].y;
            Bs[ac4 * 4 + 2][arow + r * 32] = br[r].z;
            Bs[ac4 * 4 + 3][arow + r * 32] = br[r].w;
        }
        __syncthreads();
        if (t < 7) {
            const int k0 = (t + 1) * QBK;
#pragma unroll
            for (int r = 0; r < 4; ++r)
                ar[r] = *(const float4*)(X + (size_t)(m0 + arow + r * 32) * EMB + k0 + ac4 * 4);
#pragma unroll
            for (int r = 0; r < 2; ++r)
                br[r] = *(const float4*)(W + (size_t)(n0 + arow + r * 32) * EMB + k0 + ac4 * 4);
        }
#pragma unroll
        for (int kk = 0; kk < QBK; ++kk) {
            const float4 a0 = *(const float4*)&As[kk][ty * 8];
            const float4 a1 = *(const float4*)&As[kk][ty * 8 + 4];
            const float4 bb = *(const float4*)&Bs[kk][tx * 4];
            const float am[8] = {a0.x, a0.y, a0.z, a0.w, a1.x, a1.y, a1.z, a1.w};
            const float bn[4] = {bb.x, bb.y, bb.z, bb.w};
#pragma unroll
            for (int i = 0; i < 8; ++i)
#pragma unroll
                for (int j = 0; j < 4; ++j)
                    acc[i][j] = fmaf(am[i], bn[j], acc[i][j]);
        }
    }
    // epilogue: scatter to Q (scaled) / K / V in [B,H,S,D]
    const int f0 = n0 + tx * 4;            // 4 consecutive features, same head/which
    const int which = f0 >> 8;
    const int h = (f0 & 255) >> 5, d = f0 & 31;
    float* dst = (which == 0) ? Qb : ((which == 1) ? Kb : Vb);
    const float sc = (which == 0) ? 0.17677669529663687f : 1.0f;
    const float4 b4 = *(const float4*)&bias[f0];
#pragma unroll
    for (int i = 0; i < 8; ++i) {
        const int m = m0 + ty * 8 + i;
        const int b = m >> 12, s = m & (S_LEN - 1);
        float4 v;
        v.x = (acc[i][0] + b4.x) * sc;
        v.y = (acc[i][1] + b4.y) * sc;
        v.z = (acc[i][2] + b4.z) * sc;
        v.w = (acc[i][3] + b4.w) * sc;
        *(float4*)&dst[(((size_t)b * NHEAD + h) * S_LEN + s) * HDIM + d] = v;
    }
}

// ================= OUT GEMM: C[8192,256] = A[8192,256] * W[256,256]^T =================
#define OBM 64
#define OBN 64
#define OBK 32

__global__ __launch_bounds__(256) void out_proj_kernel(
    const float* __restrict__ A, const float* __restrict__ W,
    const float* __restrict__ bias, float* __restrict__ C)
{
    __shared__ __align__(16) float As[OBK][OBM + 4]; // [32][68]
    __shared__ __align__(16) float Bs[OBK][OBN + 4];
    const int tid = threadIdx.x;
    const int tx = tid & 15, ty = tid >> 4;   // 4n, 4m
    const int m0 = blockIdx.y * OBM;
    const int n0 = blockIdx.x * OBN;
    const int arow = tid >> 3, ac4 = tid & 7;

    float4 ar[2], br[2];
#pragma unroll
    for (int r = 0; r < 2; ++r) {
        ar[r] = *(const float4*)(A + (size_t)(m0 + arow + r * 32) * EMB + ac4 * 4);
        br[r] = *(const float4*)(W + (size_t)(n0 + arow + r * 32) * EMB + ac4 * 4);
    }
    float acc[4][4] = {};
    for (int t = 0; t < 8; ++t) {
        __syncthreads();
#pragma unroll
        for (int r = 0; r < 2; ++r) {
            As[ac4 * 4 + 0][arow + r * 32] = ar[r].x;
            As[ac4 * 4 + 1][arow + r * 32] = ar[r].y;
            As[ac4 * 4 + 2][arow + r * 32] = ar[r].z;
            As[ac4 * 4 + 3][arow + r * 32] = ar[r].w;
            Bs[ac4 * 4 + 0][arow + r * 32] = br[r].x;
            Bs[ac4 * 4 + 1][arow + r * 32] = br[r].y;
            Bs[ac4 * 4 + 2][arow + r * 32] = br[r].z;
            Bs[ac4 * 4 + 3][arow + r * 32] = br[r].w;
        }
        __syncthreads();
        if (t < 7) {
            const int k0 = (t + 1) * OBK;
#pragma unroll
            for (int r = 0; r < 2; ++r) {
                ar[r] = *(const float4*)(A + (size_t)(m0 + arow + r * 32) * EMB + k0 + ac4 * 4);
                br[r] = *(const float4*)(W + (size_t)(n0 + arow + r * 32) * EMB + k0 + ac4 * 4);
            }
        }
#pragma unroll
        for (int kk = 0; kk < OBK; ++kk) {
            const float4 a = *(const float4*)&As[kk][ty * 4];
            const float4 bb = *(const float4*)&Bs[kk][tx * 4];
            const float am[4] = {a.x, a.y, a.z, a.w};
            const float bn[4] = {bb.x, bb.y, bb.z, bb.w};
#pragma unroll
            for (int i = 0; i < 4; ++i)
#pragma unroll
                for (int j = 0; j < 4; ++j)
                    acc[i][j] = fmaf(am[i], bn[j], acc[i][j]);
        }
    }
    const int f0 = n0 + tx * 4;
    const float4 b4 = *(const float4*)&bias[f0];
#pragma unroll
    for (int i = 0; i < 4; ++i) {
        const int m = m0 + ty * 4 + i;
        float4 v;
        v.x = acc[i][0] + b4.x; v.y = acc[i][1] + b4.y;
        v.z = acc[i][2] + b4.z; v.w = acc[i][3] + b4.w;
        *(float4*)(C + (size_t)m * EMB + f0) = v;
    }
}

// ================= Banded attention: two-phase register-tiled =================
#define KT_STRIDE 204
#define PS_STRIDE 196
#define VS_STRIDE 36
#define QT_STRIDE 68

__global__ __launch_bounds__(256) void local_attn_kernel(
    const float* __restrict__ Qb, const float* __restrict__ Kb,
    const float* __restrict__ Vb, float* __restrict__ Ab)
{
    __shared__ __align__(16) float SA[192 * VS_STRIDE];   // Qt[32][68] then Vs[192][36]
    __shared__ __align__(16) float SB[64 * PS_STRIDE];    // Kt[32][204] then Ps[64][196]
    __shared__ float Lrs[64];
    const int tid = threadIdx.x;
    const int q0 = blockIdx.x * 64;
    const int h = blockIdx.y, b = blockIdx.z;
    const int jmin = max(0, q0 - WIN);
    const int jmax = min(S_LEN - 1, q0 + 63 + WIN);
    const int nk = jmax - jmin + 1;                       // <= 192
    const size_t bhS = ((size_t)b * NHEAD + h) * S_LEN;
    const float* Qg = Qb + (bhS + q0) * HDIM;             // Q pre-scaled by 1/sqrt(D)
    const float* Kg = Kb + (bhS + jmin) * HDIM;
    const float* Vg = Vb + (bhS + jmin) * HDIM;

    float* Qt = SA;   // [dim][query]
    float* Vs = SA;   // [key][dim]   (after phase 1)
    float* Kt = SB;   // [dim][key]
    float* Ps = SB;   // [query][key] (after phase 1)

    const int r0 = tid >> 3, c4 = tid & 7;
    // stage Q transposed: 64 rows x 32 dims
#pragma unroll
    for (int r = 0; r < 2; ++r) {
        const int row = r0 + r * 32;
        const float4 v = *(const float4*)&Qg[row * HDIM + c4 * 4];
        Qt[(c4 * 4 + 0) * QT_STRIDE + row] = v.x;
        Qt[(c4 * 4 + 1) * QT_STRIDE + row] = v.y;
        Qt[(c4 * 4 + 2) * QT_STRIDE + row] = v.z;
        Qt[(c4 * 4 + 3) * QT_STRIDE + row] = v.w;
    }
    // stage K transposed: 192 key slots (clamped in-bounds; tails masked later)
#pragma unroll
    for (int r = 0; r < 6; ++r) {
        const int t = r0 + r * 32;
        const int tc = min(t, nk - 1);
        const float4 v = *(const float4*)&Kg[tc * HDIM + c4 * 4];
        Kt[(c4 * 4 + 0) * KT_STRIDE + t] = v.x;
        Kt[(c4 * 4 + 1) * KT_STRIDE + t] = v.y;
        Kt[(c4 * 4 + 2) * KT_STRIDE + t] = v.z;
        Kt[(c4 * 4 + 3) * KT_STRIDE + t] = v.w;
    }
    __syncthreads();

    // ---- phase 1: S[64,192] = Q · K^T, per-thread 4q x 12k ----
    const int tx = tid & 15, ty = tid >> 4;
    float s[4][12] = {};
#pragma unroll 4
    for (int kk = 0; kk < 32; ++kk) {
        const float4 qf = *(const float4*)&Qt[kk * QT_STRIDE + ty * 4];
        const float4 k0f = *(const float4*)&Kt[kk * KT_STRIDE + tx * 12];
        const float4 k1f = *(const float4*)&Kt[kk * KT_STRIDE + tx * 12 + 4];
        const float4 k2f = *(const float4*)&Kt[kk * KT_STRIDE + tx * 12 + 8];
        const float qm[4] = {qf.x, qf.y, qf.z, qf.w};
        const float kn[12] = {k0f.x, k0f.y, k0f.z, k0f.w,
                              k1f.x, k1f.y, k1f.z, k1f.w,
                              k2f.x, k2f.y, k2f.z, k2f.w};
#pragma unroll
        for (int qi = 0; qi < 4; ++qi)
#pragma unroll
            for (int jj = 0; jj < 12; ++jj)
                s[qi][jj] = fmaf(qm[qi], kn[jj], s[qi][jj]);
    }
    // mask + online-free softmax (full row available)
    float mx[4], l[4];
#pragma unroll
    for (int qi = 0; qi < 4; ++qi) {
        const int q = q0 + ty * 4 + qi;
        float m = -1e30f;
#pragma unroll
        for (int jj = 0; jj < 12; ++jj) {
            const int j = jmin + tx * 12 + jj;
            const bool valid = (j >= q - WIN) && (j <= q + WIN) && (j <= jmax);
            const float sv = valid ? s[qi][jj] : -1e30f;
            s[qi][jj] = sv;
            m = fmaxf(m, sv);
        }
        m = fmaxf(m, __shfl_xor(m, 1));
        m = fmaxf(m, __shfl_xor(m, 2));
        m = fmaxf(m, __shfl_xor(m, 4));
        m = fmaxf(m, __shfl_xor(m, 8));
        mx[qi] = m;
        float ls = 0.f;
#pragma unroll
        for (int jj = 0; jj < 12; ++jj) {
            const float e = __expf(s[qi][jj] - m);
            s[qi][jj] = e;
            ls += e;
        }
        ls += __shfl_xor(ls, 1);
        ls += __shfl_xor(ls, 2);
        ls += __shfl_xor(ls, 4);
        ls += __shfl_xor(ls, 8);
        l[qi] = ls;
    }
    __syncthreads();  // everyone done reading Qt/Kt

    // write P (row-major), reciprocal row-sums, stage V
#pragma unroll
    for (int qi = 0; qi < 4; ++qi) {
        float* pr = &Ps[(ty * 4 + qi) * PS_STRIDE + tx * 12];
        float4 w0, w1, w2;
        w0.x = s[qi][0]; w0.y = s[qi][1]; w0.z = s[qi][2]; w0.w = s[qi][3];
        w1.x = s[qi][4]; w1.y = s[qi][5]; w1.z = s[qi][6]; w1.w = s[qi][7];
        w2.x = s[qi][8]; w2.y = s[qi][9]; w2.z = s[qi][10]; w2.w = s[qi][11];
        *(float4*)(pr + 0) = w0;
        *(float4*)(pr + 4) = w1;
        *(float4*)(pr + 8) = w2;
    }
    if (tx == 0) {
#pragma unroll
        for (int qi = 0; qi < 4; ++qi) Lrs[ty * 4 + qi] = 1.f / l[qi];
    }
#pragma unroll
    for (int r = 0; r < 6; ++r) {
        const int t = r0 + r * 32;
        const int tc = min(t, nk - 1);
        const float4 v = *(const float4*)&Vg[tc * HDIM + c4 * 4];
        *(float4*)&Vs[t * VS_STRIDE + c4 * 4] = v;
    }
    __syncthreads();

    // ---- phase 2: O[64,32] = P · V, one query per lane, dim-slice per wave ----
    const int q = tid & 63, dg = tid >> 6;
    const float rl = Lrs[q];
    float o[8] = {};
    const float* prow = &Ps[q * PS_STRIDE];
#pragma unroll 4
    for (int kc = 0; kc < 48; ++kc) {
        const float4 p4 = *(const float4*)(prow + kc * 4);
        const float pf[4] = {p4.x, p4.y, p4.z, p4.w};
#pragma unroll
        for (int jj = 0; jj < 4; ++jj) {
            const int k = kc * 4 + jj;
            const float4 v0 = *(const float4*)&Vs[k * VS_STRIDE + dg * 8];
            const float4 v1 = *(const float4*)&Vs[k * VS_STRIDE + dg * 8 + 4];
            o[0] = fmaf(pf[jj], v0.x, o[0]);
            o[1] = fmaf(pf[jj], v0.y, o[1]);
            o[2] = fmaf(pf[jj], v0.z, o[2]);
            o[3] = fmaf(pf[jj], v0.w, o[3]);
            o[4] = fmaf(pf[jj], v1.x, o[4]);
            o[5] = fmaf(pf[jj], v1.y, o[5]);
            o[6] = fmaf(pf[jj], v1.z, o[6]);
            o[7] = fmaf(pf[jj], v1.w, o[7]);
        }
    }
    float* og = Ab + ((size_t)b * S_LEN + q0 + q) * EMB + h * HDIM + dg * 8;
    float4 w0, w1;
    w0.x = o[0] * rl; w0.y = o[1] * rl; w0.z = o[2] * rl; w0.w = o[3] * rl;
    w1.x = o[4] * rl; w1.y = o[5] * rl; w1.z = o[6] * rl; w1.w = o[7] * rl;
    *(float4*)og = w0;
    *(float4*)(og + 4) = w1;
}

extern "C" void kernel_launch(void* const* d_in, const int* in_sizes, int n_in,
                              void* d_out, int out_size, void* d_ws, size_t ws_size,
                              hipStream_t stream) {
    const float* x  = (const float*)d_in[0];
    const float* wi = (const float*)d_in[1];
    const float* bi = (const float*)d_in[2];
    const float* wo = (const float*)d_in[3];
    const float* bo = (const float*)d_in[4];
    float* out = (float*)d_out;

    const size_t per = (size_t)BATCH * NHEAD * S_LEN * HDIM;
    float* Qb = (float*)d_ws;
    float* Kb = Qb + per;
    float* Vb = Kb + per;
    float* Ab = Vb + per;

    qkv_proj_kernel<<<dim3(768 / QBN, 8192 / QBM), 256, 0, stream>>>(x, wi, bi, Qb, Kb, Vb);
    local_attn_kernel<<<dim3(S_LEN / 64, NHEAD, BATCH), 256, 0, stream>>>(Qb, Kb, Vb, Ab);
    out_proj_kernel<<<dim3(256 / OBN, 8192 / OBM), 256, 0, stream>>>(Ab, wo, bo, out);
}

// Round 3
// 131.576 us; speedup vs baseline: 1.2491x; 1.1940x over previous
//
#include <hip/hip_runtime.h>
#include <hip/hip_bf16.h>

#define S_LEN 4096
#define EMB   256
#define NHEAD 8
#define HDIM  32
#define WIN   64
#define BATCH 2

typedef __attribute__((ext_vector_type(8))) short short8;
typedef __attribute__((ext_vector_type(4))) float floatx4;

// ---- split-precision bf16 helpers: x = hi + lo + O(2^-18 |x|) ----
static __device__ __forceinline__ unsigned int bf16_rn(float x) {
    unsigned int u = __float_as_uint(x);
    return (u + 0x7FFFu + ((u >> 16) & 1u)) >> 16;
}
static __device__ __forceinline__ void split2(float x, unsigned int& hi, unsigned int& lo) {
    hi = bf16_rn(x);
    const float hf = __uint_as_float(hi << 16);
    lo = bf16_rn(x - hf);
}
static __device__ __forceinline__ void split_store4(unsigned short* hp, unsigned short* lp, float4 v) {
    unsigned int h0, l0, h1, l1, h2, l2, h3, l3;
    split2(v.x, h0, l0); split2(v.y, h1, l1);
    split2(v.z, h2, l2); split2(v.w, h3, l3);
    uint2 hv, lv;
    hv.x = h0 | (h1 << 16); hv.y = h2 | (h3 << 16);
    lv.x = l0 | (l1 << 16); lv.y = l2 | (l3 << 16);
    *(uint2*)hp = hv;
    *(uint2*)lp = lv;
}

// ============ QKV GEMM (MFMA split-bf16): C[8192,768] = X[8192,256] * W[768,256]^T ============
// block tile 128m x 64n, K-step 32, 4 waves in 2x2 (64m x 32n each), 4x2 16x16 acc tiles/wave.
#define LDA 40  // bf16 row stride: 80B, 16B-aligned, 2-way-free frag reads

__global__ __launch_bounds__(256) void qkv_proj_kernel(
    const float* __restrict__ X, const float* __restrict__ W,
    const float* __restrict__ bias,
    float* __restrict__ Qb, float* __restrict__ Kb, float* __restrict__ Vb)
{
    __shared__ __align__(16) unsigned short Ah[128 * LDA], Al[128 * LDA];
    __shared__ __align__(16) unsigned short Bh[64 * LDA],  Bl[64 * LDA];
    const int tid = threadIdx.x;
    const int m0 = blockIdx.y * 128, n0 = blockIdx.x * 64;
    const int r0 = tid >> 3, c4 = tid & 7;      // staging: row base, float4 col
    const int lane = tid & 63, wv = tid >> 6;
    const int wm = (wv >> 1) * 64, wn = (wv & 1) * 32;
    const int lm = lane & 15, kq = lane >> 4;

    float4 ar[4], wr[2];
#pragma unroll
    for (int r = 0; r < 4; ++r)
        ar[r] = *(const float4*)(X + (size_t)(m0 + r0 + r * 32) * EMB + c4 * 4);
#pragma unroll
    for (int r = 0; r < 2; ++r)
        wr[r] = *(const float4*)(W + (size_t)(n0 + r0 + r * 32) * EMB + c4 * 4);

    floatx4 acc[4][2] = {};
    for (int t = 0; t < 8; ++t) {
        __syncthreads();
#pragma unroll
        for (int r = 0; r < 4; ++r)
            split_store4(&Ah[(r0 + r * 32) * LDA + c4 * 4], &Al[(r0 + r * 32) * LDA + c4 * 4], ar[r]);
#pragma unroll
        for (int r = 0; r < 2; ++r)
            split_store4(&Bh[(r0 + r * 32) * LDA + c4 * 4], &Bl[(r0 + r * 32) * LDA + c4 * 4], wr[r]);
        __syncthreads();
        if (t < 7) {
            const int k0 = (t + 1) * 32;
#pragma unroll
            for (int r = 0; r < 4; ++r)
                ar[r] = *(const float4*)(X + (size_t)(m0 + r0 + r * 32) * EMB + k0 + c4 * 4);
#pragma unroll
            for (int r = 0; r < 2; ++r)
                wr[r] = *(const float4*)(W + (size_t)(n0 + r0 + r * 32) * EMB + k0 + c4 * 4);
        }
        short8 a_h[4], a_l[4], b_h[2], b_l[2];
#pragma unroll
        for (int mt = 0; mt < 4; ++mt) {
            a_h[mt] = *(const short8*)&Ah[(wm + mt * 16 + lm) * LDA + kq * 8];
            a_l[mt] = *(const short8*)&Al[(wm + mt * 16 + lm) * LDA + kq * 8];
        }
#pragma unroll
        for (int nt = 0; nt < 2; ++nt) {
            b_h[nt] = *(const short8*)&Bh[(wn + nt * 16 + lm) * LDA + kq * 8];
            b_l[nt] = *(const short8*)&Bl[(wn + nt * 16 + lm) * LDA + kq * 8];
        }
#pragma unroll
        for (int mt = 0; mt < 4; ++mt)
#pragma unroll
            for (int nt = 0; nt < 2; ++nt) {
                acc[mt][nt] = __builtin_amdgcn_mfma_f32_16x16x32_bf16(a_h[mt], b_h[nt], acc[mt][nt], 0, 0, 0);
                acc[mt][nt] = __builtin_amdgcn_mfma_f32_16x16x32_bf16(a_h[mt], b_l[nt], acc[mt][nt], 0, 0, 0);
                acc[mt][nt] = __builtin_amdgcn_mfma_f32_16x16x32_bf16(a_l[mt], b_h[nt], acc[mt][nt], 0, 0, 0);
            }
    }
    // epilogue: C/D layout col=lane&15, row=(lane>>4)*4+reg
#pragma unroll
    for (int nt = 0; nt < 2; ++nt) {
        const int f = n0 + wn + nt * 16 + lm;
        const int which = f >> 8;
        const int h = (f & 255) >> 5, d = f & 31;
        float* dst = (which == 0) ? Qb : ((which == 1) ? Kb : Vb);
        const float sc = (which == 0) ? 0.17677669529663687f : 1.0f;
        const float bf = bias[f];
#pragma unroll
        for (int mt = 0; mt < 4; ++mt)
#pragma unroll
            for (int r = 0; r < 4; ++r) {
                const int m = m0 + wm + mt * 16 + kq * 4 + r;
                const int b = m >> 12, s = m & (S_LEN - 1);
                dst[(((size_t)b * NHEAD + h) * S_LEN + s) * HDIM + d] = (acc[mt][nt][r] + bf) * sc;
            }
    }
}

// ============ OUT GEMM (MFMA split-bf16): C[8192,256] = A[8192,256] * W[256,256]^T ============
__global__ __launch_bounds__(256) void out_proj_kernel(
    const float* __restrict__ A, const float* __restrict__ W,
    const float* __restrict__ bias, float* __restrict__ C)
{
    __shared__ __align__(16) unsigned short Ah[128 * LDA], Al[128 * LDA];
    __shared__ __align__(16) unsigned short Bh[64 * LDA],  Bl[64 * LDA];
    const int tid = threadIdx.x;
    const int m0 = blockIdx.y * 128, n0 = blockIdx.x * 64;
    const int r0 = tid >> 3, c4 = tid & 7;
    const int lane = tid & 63, wv = tid >> 6;
    const int wm = (wv >> 1) * 64, wn = (wv & 1) * 32;
    const int lm = lane & 15, kq = lane >> 4;

    float4 ar[4], wr[2];
#pragma unroll
    for (int r = 0; r < 4; ++r)
        ar[r] = *(const float4*)(A + (size_t)(m0 + r0 + r * 32) * EMB + c4 * 4);
#pragma unroll
    for (int r = 0; r < 2; ++r)
        wr[r] = *(const float4*)(W + (size_t)(n0 + r0 + r * 32) * EMB + c4 * 4);

    floatx4 acc[4][2] = {};
    for (int t = 0; t < 8; ++t) {
        __syncthreads();
#pragma unroll
        for (int r = 0; r < 4; ++r)
            split_store4(&Ah[(r0 + r * 32) * LDA + c4 * 4], &Al[(r0 + r * 32) * LDA + c4 * 4], ar[r]);
#pragma unroll
        for (int r = 0; r < 2; ++r)
            split_store4(&Bh[(r0 + r * 32) * LDA + c4 * 4], &Bl[(r0 + r * 32) * LDA + c4 * 4], wr[r]);
        __syncthreads();
        if (t < 7) {
            const int k0 = (t + 1) * 32;
#pragma unroll
            for (int r = 0; r < 4; ++r)
                ar[r] = *(const float4*)(A + (size_t)(m0 + r0 + r * 32) * EMB + k0 + c4 * 4);
#pragma unroll
            for (int r = 0; r < 2; ++r)
                wr[r] = *(const float4*)(W + (size_t)(n0 + r0 + r * 32) * EMB + k0 + c4 * 4);
        }
        short8 a_h[4], a_l[4], b_h[2], b_l[2];
#pragma unroll
        for (int mt = 0; mt < 4; ++mt) {
            a_h[mt] = *(const short8*)&Ah[(wm + mt * 16 + lm) * LDA + kq * 8];
            a_l[mt] = *(const short8*)&Al[(wm + mt * 16 + lm) * LDA + kq * 8];
        }
#pragma unroll
        for (int nt = 0; nt < 2; ++nt) {
            b_h[nt] = *(const short8*)&Bh[(wn + nt * 16 + lm) * LDA + kq * 8];
            b_l[nt] = *(const short8*)&Bl[(wn + nt * 16 + lm) * LDA + kq * 8];
        }
#pragma unroll
        for (int mt = 0; mt < 4; ++mt)
#pragma unroll
            for (int nt = 0; nt < 2; ++nt) {
                acc[mt][nt] = __builtin_amdgcn_mfma_f32_16x16x32_bf16(a_h[mt], b_h[nt], acc[mt][nt], 0, 0, 0);
                acc[mt][nt] = __builtin_amdgcn_mfma_f32_16x16x32_bf16(a_h[mt], b_l[nt], acc[mt][nt], 0, 0, 0);
                acc[mt][nt] = __builtin_amdgcn_mfma_f32_16x16x32_bf16(a_l[mt], b_h[nt], acc[mt][nt], 0, 0, 0);
            }
    }
#pragma unroll
    for (int nt = 0; nt < 2; ++nt) {
        const int f = n0 + wn + nt * 16 + lm;
        const float bf = bias[f];
#pragma unroll
        for (int mt = 0; mt < 4; ++mt)
#pragma unroll
            for (int r = 0; r < 4; ++r) {
                const int m = m0 + wm + mt * 16 + kq * 4 + r;
                C[(size_t)m * EMB + f] = acc[mt][nt][r] + bf;
            }
    }
}

// ================= Banded attention (unchanged from R2) =================
#define KT_STRIDE 204
#define PS_STRIDE 196
#define VS_STRIDE 36
#define QT_STRIDE 68

__global__ __launch_bounds__(256) void local_attn_kernel(
    const float* __restrict__ Qb, const float* __restrict__ Kb,
    const float* __restrict__ Vb, float* __restrict__ Ab)
{
    __shared__ __align__(16) float SA[192 * VS_STRIDE];
    __shared__ __align__(16) float SB[64 * PS_STRIDE];
    __shared__ float Lrs[64];
    const int tid = threadIdx.x;
    const int q0 = blockIdx.x * 64;
    const int h = blockIdx.y, b = blockIdx.z;
    const int jmin = max(0, q0 - WIN);
    const int jmax = min(S_LEN - 1, q0 + 63 + WIN);
    const int nk = jmax - jmin + 1;
    const size_t bhS = ((size_t)b * NHEAD + h) * S_LEN;
    const float* Qg = Qb + (bhS + q0) * HDIM;
    const float* Kg = Kb + (bhS + jmin) * HDIM;
    const float* Vg = Vb + (bhS + jmin) * HDIM;

    float* Qt = SA;
    float* Vs = SA;
    float* Kt = SB;
    float* Ps = SB;

    const int r0 = tid >> 3, c4 = tid & 7;
#pragma unroll
    for (int r = 0; r < 2; ++r) {
        const int row = r0 + r * 32;
        const float4 v = *(const float4*)&Qg[row * HDIM + c4 * 4];
        Qt[(c4 * 4 + 0) * QT_STRIDE + row] = v.x;
        Qt[(c4 * 4 + 1) * QT_STRIDE + row] = v.y;
        Qt[(c4 * 4 + 2) * QT_STRIDE + row] = v.z;
        Qt[(c4 * 4 + 3) * QT_STRIDE + row] = v.w;
    }
#pragma unroll
    for (int r = 0; r < 6; ++r) {
        const int t = r0 + r * 32;
        const int tc = min(t, nk - 1);
        const float4 v = *(const float4*)&Kg[tc * HDIM + c4 * 4];
        Kt[(c4 * 4 + 0) * KT_STRIDE + t] = v.x;
        Kt[(c4 * 4 + 1) * KT_STRIDE + t] = v.y;
        Kt[(c4 * 4 + 2) * KT_STRIDE + t] = v.z;
        Kt[(c4 * 4 + 3) * KT_STRIDE + t] = v.w;
    }
    __syncthreads();

    const int tx = tid & 15, ty = tid >> 4;
    float s[4][12] = {};
#pragma unroll 4
    for (int kk = 0; kk < 32; ++kk) {
        const float4 qf = *(const float4*)&Qt[kk * QT_STRIDE + ty * 4];
        const float4 k0f = *(const float4*)&Kt[kk * KT_STRIDE + tx * 12];
        const float4 k1f = *(const float4*)&Kt[kk * KT_STRIDE + tx * 12 + 4];
        const float4 k2f = *(const float4*)&Kt[kk * KT_STRIDE + tx * 12 + 8];
        const float qm[4] = {qf.x, qf.y, qf.z, qf.w};
        const float kn[12] = {k0f.x, k0f.y, k0f.z, k0f.w,
                              k1f.x, k1f.y, k1f.z, k1f.w,
                              k2f.x, k2f.y, k2f.z, k2f.w};
#pragma unroll
        for (int qi = 0; qi < 4; ++qi)
#pragma unroll
            for (int jj = 0; jj < 12; ++jj)
                s[qi][jj] = fmaf(qm[qi], kn[jj], s[qi][jj]);
    }
    float l[4];
#pragma unroll
    for (int qi = 0; qi < 4; ++qi) {
        const int q = q0 + ty * 4 + qi;
        float m = -1e30f;
#pragma unroll
        for (int jj = 0; jj < 12; ++jj) {
            const int j = jmin + tx * 12 + jj;
            const bool valid = (j >= q - WIN) && (j <= q + WIN) && (j <= jmax);
            const float sv = valid ? s[qi][jj] : -1e30f;
            s[qi][jj] = sv;
            m = fmaxf(m, sv);
        }
        m = fmaxf(m, __shfl_xor(m, 1));
        m = fmaxf(m, __shfl_xor(m, 2));
        m = fmaxf(m, __shfl_xor(m, 4));
        m = fmaxf(m, __shfl_xor(m, 8));
        float ls = 0.f;
#pragma unroll
        for (int jj = 0; jj < 12; ++jj) {
            const float e = __expf(s[qi][jj] - m);
            s[qi][jj] = e;
            ls += e;
        }
        ls += __shfl_xor(ls, 1);
        ls += __shfl_xor(ls, 2);
        ls += __shfl_xor(ls, 4);
        ls += __shfl_xor(ls, 8);
        l[qi] = ls;
    }
    __syncthreads();

#pragma unroll
    for (int qi = 0; qi < 4; ++qi) {
        float* pr = &Ps[(ty * 4 + qi) * PS_STRIDE + tx * 12];
        float4 w0, w1, w2;
        w0.x = s[qi][0]; w0.y = s[qi][1]; w0.z = s[qi][2]; w0.w = s[qi][3];
        w1.x = s[qi][4]; w1.y = s[qi][5]; w1.z = s[qi][6]; w1.w = s[qi][7];
        w2.x = s[qi][8]; w2.y = s[qi][9]; w2.z = s[qi][10]; w2.w = s[qi][11];
        *(float4*)(pr + 0) = w0;
        *(float4*)(pr + 4) = w1;
        *(float4*)(pr + 8) = w2;
    }
    if (tx == 0) {
#pragma unroll
        for (int qi = 0; qi < 4; ++qi) Lrs[ty * 4 + qi] = 1.f / l[qi];
    }
#pragma unroll
    for (int r = 0; r < 6; ++r) {
        const int t = r0 + r * 32;
        const int tc = min(t, nk - 1);
        const float4 v = *(const float4*)&Vg[tc * HDIM + c4 * 4];
        *(float4*)&Vs[t * VS_STRIDE + c4 * 4] = v;
    }
    __syncthreads();

    const int q = tid & 63, dg = tid >> 6;
    const float rl = Lrs[q];
    float o[8] = {};
    const float* prow = &Ps[q * PS_STRIDE];
#pragma unroll 4
    for (int kc = 0; kc < 48; ++kc) {
        const float4 p4 = *(const float4*)(prow + kc * 4);
        const float pf[4] = {p4.x, p4.y, p4.z, p4.w};
#pragma unroll
        for (int jj = 0; jj < 4; ++jj) {
            const int k = kc * 4 + jj;
            const float4 v0 = *(const float4*)&Vs[k * VS_STRIDE + dg * 8];
            const float4 v1 = *(const float4*)&Vs[k * VS_STRIDE + dg * 8 + 4];
            o[0] = fmaf(pf[jj], v0.x, o[0]);
            o[1] = fmaf(pf[jj], v0.y, o[1]);
            o[2] = fmaf(pf[jj], v0.z, o[2]);
            o[3] = fmaf(pf[jj], v0.w, o[3]);
            o[4] = fmaf(pf[jj], v1.x, o[4]);
            o[5] = fmaf(pf[jj], v1.y, o[5]);
            o[6] = fmaf(pf[jj], v1.z, o[6]);
            o[7] = fmaf(pf[jj], v1.w, o[7]);
        }
    }
    float* og = Ab + ((size_t)b * S_LEN + q0 + q) * EMB + h * HDIM + dg * 8;
    float4 w0, w1;
    w0.x = o[0] * rl; w0.y = o[1] * rl; w0.z = o[2] * rl; w0.w = o[3] * rl;
    w1.x = o[4] * rl; w1.y = o[5] * rl; w1.z = o[6] * rl; w1.w = o[7] * rl;
    *(float4*)og = w0;
    *(float4*)(og + 4) = w1;
}

extern "C" void kernel_launch(void* const* d_in, const int* in_sizes, int n_in,
                              void* d_out, int out_size, void* d_ws, size_t ws_size,
                              hipStream_t stream) {
    const float* x  = (const float*)d_in[0];
    const float* wi = (const float*)d_in[1];
    const float* bi = (const float*)d_in[2];
    const float* wo = (const float*)d_in[3];
    const float* bo = (const float*)d_in[4];
    float* out = (float*)d_out;

    const size_t per = (size_t)BATCH * NHEAD * S_LEN * HDIM;
    float* Qb = (float*)d_ws;
    float* Kb = Qb + per;
    float* Vb = Kb + per;
    float* Ab = Vb + per;

    qkv_proj_kernel<<<dim3(768 / 64, 8192 / 128), 256, 0, stream>>>(x, wi, bi, Qb, Kb, Vb);
    local_attn_kernel<<<dim3(S_LEN / 64, NHEAD, BATCH), 256, 0, stream>>>(Qb, Kb, Vb, Ab);
    out_proj_kernel<<<dim3(256 / 64, 8192 / 128), 256, 0, stream>>>(Ab, wo, bo, out);
}

// Round 4
// 116.992 us; speedup vs baseline: 1.4049x; 1.1247x over previous
//
#include <hip/hip_runtime.h>
#include <hip/hip_bf16.h>

#define S_LEN 4096
#define EMB   256
#define NHEAD 8
#define HDIM  32
#define WIN   64
#define BATCH 2

typedef __attribute__((ext_vector_type(8))) short short8;
typedef __attribute__((ext_vector_type(4))) float floatx4;

// ---- split-precision bf16 helpers: x = hi + lo + O(2^-18 |x|) ----
static __device__ __forceinline__ unsigned int bf16_rn(float x) {
    unsigned int u = __float_as_uint(x);
    return (u + 0x7FFFu + ((u >> 16) & 1u)) >> 16;
}
static __device__ __forceinline__ void split2(float x, unsigned int& hi, unsigned int& lo) {
    hi = bf16_rn(x);
    const float hf = __uint_as_float(hi << 16);
    lo = bf16_rn(x - hf);
}
static __device__ __forceinline__ void split_store4(unsigned short* hp, unsigned short* lp, float4 v) {
    unsigned int h0, l0, h1, l1, h2, l2, h3, l3;
    split2(v.x, h0, l0); split2(v.y, h1, l1);
    split2(v.z, h2, l2); split2(v.w, h3, l3);
    uint2 hv, lv;
    hv.x = h0 | (h1 << 16); hv.y = h2 | (h3 << 16);
    lv.x = l0 | (l1 << 16); lv.y = l2 | (l3 << 16);
    *(uint2*)hp = hv;
    *(uint2*)lp = lv;
}

// ============ QKV GEMM (MFMA split-bf16): C[8192,768] = X[8192,256] * W[768,256]^T ============
#define LDA 40  // bf16 row stride: 80B, 16B-aligned

__global__ __launch_bounds__(256) void qkv_proj_kernel(
    const float* __restrict__ X, const float* __restrict__ W,
    const float* __restrict__ bias,
    float* __restrict__ Qb, float* __restrict__ Kb, float* __restrict__ Vb)
{
    __shared__ __align__(16) unsigned short Ah[128 * LDA], Al[128 * LDA];
    __shared__ __align__(16) unsigned short Bh[64 * LDA],  Bl[64 * LDA];
    const int tid = threadIdx.x;
    const int m0 = blockIdx.y * 128, n0 = blockIdx.x * 64;
    const int r0 = tid >> 3, c4 = tid & 7;
    const int lane = tid & 63, wv = tid >> 6;
    const int wm = (wv >> 1) * 64, wn = (wv & 1) * 32;
    const int lm = lane & 15, kq = lane >> 4;

    float4 ar[4], wr[2];
#pragma unroll
    for (int r = 0; r < 4; ++r)
        ar[r] = *(const float4*)(X + (size_t)(m0 + r0 + r * 32) * EMB + c4 * 4);
#pragma unroll
    for (int r = 0; r < 2; ++r)
        wr[r] = *(const float4*)(W + (size_t)(n0 + r0 + r * 32) * EMB + c4 * 4);

    floatx4 acc[4][2] = {};
    for (int t = 0; t < 8; ++t) {
        __syncthreads();
#pragma unroll
        for (int r = 0; r < 4; ++r)
            split_store4(&Ah[(r0 + r * 32) * LDA + c4 * 4], &Al[(r0 + r * 32) * LDA + c4 * 4], ar[r]);
#pragma unroll
        for (int r = 0; r < 2; ++r)
            split_store4(&Bh[(r0 + r * 32) * LDA + c4 * 4], &Bl[(r0 + r * 32) * LDA + c4 * 4], wr[r]);
        __syncthreads();
        if (t < 7) {
            const int k0 = (t + 1) * 32;
#pragma unroll
            for (int r = 0; r < 4; ++r)
                ar[r] = *(const float4*)(X + (size_t)(m0 + r0 + r * 32) * EMB + k0 + c4 * 4);
#pragma unroll
            for (int r = 0; r < 2; ++r)
                wr[r] = *(const float4*)(W + (size_t)(n0 + r0 + r * 32) * EMB + k0 + c4 * 4);
        }
        short8 a_h[4], a_l[4], b_h[2], b_l[2];
#pragma unroll
        for (int mt = 0; mt < 4; ++mt) {
            a_h[mt] = *(const short8*)&Ah[(wm + mt * 16 + lm) * LDA + kq * 8];
            a_l[mt] = *(const short8*)&Al[(wm + mt * 16 + lm) * LDA + kq * 8];
        }
#pragma unroll
        for (int nt = 0; nt < 2; ++nt) {
            b_h[nt] = *(const short8*)&Bh[(wn + nt * 16 + lm) * LDA + kq * 8];
            b_l[nt] = *(const short8*)&Bl[(wn + nt * 16 + lm) * LDA + kq * 8];
        }
#pragma unroll
        for (int mt = 0; mt < 4; ++mt)
#pragma unroll
            for (int nt = 0; nt < 2; ++nt) {
                acc[mt][nt] = __builtin_amdgcn_mfma_f32_16x16x32_bf16(a_h[mt], b_h[nt], acc[mt][nt], 0, 0, 0);
                acc[mt][nt] = __builtin_amdgcn_mfma_f32_16x16x32_bf16(a_h[mt], b_l[nt], acc[mt][nt], 0, 0, 0);
                acc[mt][nt] = __builtin_amdgcn_mfma_f32_16x16x32_bf16(a_l[mt], b_h[nt], acc[mt][nt], 0, 0, 0);
            }
    }
#pragma unroll
    for (int nt = 0; nt < 2; ++nt) {
        const int f = n0 + wn + nt * 16 + lm;
        const int which = f >> 8;
        const int h = (f & 255) >> 5, d = f & 31;
        float* dst = (which == 0) ? Qb : ((which == 1) ? Kb : Vb);
        const float sc = (which == 0) ? 0.17677669529663687f : 1.0f;
        const float bf = bias[f];
#pragma unroll
        for (int mt = 0; mt < 4; ++mt)
#pragma unroll
            for (int r = 0; r < 4; ++r) {
                const int m = m0 + wm + mt * 16 + kq * 4 + r;
                const int b = m >> 12, s = m & (S_LEN - 1);
                dst[(((size_t)b * NHEAD + h) * S_LEN + s) * HDIM + d] = (acc[mt][nt][r] + bf) * sc;
            }
    }
}

// ============ OUT GEMM (MFMA split-bf16): C[8192,256] = A[8192,256] * W[256,256]^T ============
__global__ __launch_bounds__(256) void out_proj_kernel(
    const float* __restrict__ A, const float* __restrict__ W,
    const float* __restrict__ bias, float* __restrict__ C)
{
    __shared__ __align__(16) unsigned short Ah[128 * LDA], Al[128 * LDA];
    __shared__ __align__(16) unsigned short Bh[64 * LDA],  Bl[64 * LDA];
    const int tid = threadIdx.x;
    const int m0 = blockIdx.y * 128, n0 = blockIdx.x * 64;
    const int r0 = tid >> 3, c4 = tid & 7;
    const int lane = tid & 63, wv = tid >> 6;
    const int wm = (wv >> 1) * 64, wn = (wv & 1) * 32;
    const int lm = lane & 15, kq = lane >> 4;

    float4 ar[4], wr[2];
#pragma unroll
    for (int r = 0; r < 4; ++r)
        ar[r] = *(const float4*)(A + (size_t)(m0 + r0 + r * 32) * EMB + c4 * 4);
#pragma unroll
    for (int r = 0; r < 2; ++r)
        wr[r] = *(const float4*)(W + (size_t)(n0 + r0 + r * 32) * EMB + c4 * 4);

    floatx4 acc[4][2] = {};
    for (int t = 0; t < 8; ++t) {
        __syncthreads();
#pragma unroll
        for (int r = 0; r < 4; ++r)
            split_store4(&Ah[(r0 + r * 32) * LDA + c4 * 4], &Al[(r0 + r * 32) * LDA + c4 * 4], ar[r]);
#pragma unroll
        for (int r = 0; r < 2; ++r)
            split_store4(&Bh[(r0 + r * 32) * LDA + c4 * 4], &Bl[(r0 + r * 32) * LDA + c4 * 4], wr[r]);
        __syncthreads();
        if (t < 7) {
            const int k0 = (t + 1) * 32;
#pragma unroll
            for (int r = 0; r < 4; ++r)
                ar[r] = *(const float4*)(A + (size_t)(m0 + r0 + r * 32) * EMB + k0 + c4 * 4);
#pragma unroll
            for (int r = 0; r < 2; ++r)
                wr[r] = *(const float4*)(W + (size_t)(n0 + r0 + r * 32) * EMB + k0 + c4 * 4);
        }
        short8 a_h[4], a_l[4], b_h[2], b_l[2];
#pragma unroll
        for (int mt = 0; mt < 4; ++mt) {
            a_h[mt] = *(const short8*)&Ah[(wm + mt * 16 + lm) * LDA + kq * 8];
            a_l[mt] = *(const short8*)&Al[(wm + mt * 16 + lm) * LDA + kq * 8];
        }
#pragma unroll
        for (int nt = 0; nt < 2; ++nt) {
            b_h[nt] = *(const short8*)&Bh[(wn + nt * 16 + lm) * LDA + kq * 8];
            b_l[nt] = *(const short8*)&Bl[(wn + nt * 16 + lm) * LDA + kq * 8];
        }
#pragma unroll
        for (int mt = 0; mt < 4; ++mt)
#pragma unroll
            for (int nt = 0; nt < 2; ++nt) {
                acc[mt][nt] = __builtin_amdgcn_mfma_f32_16x16x32_bf16(a_h[mt], b_h[nt], acc[mt][nt], 0, 0, 0);
                acc[mt][nt] = __builtin_amdgcn_mfma_f32_16x16x32_bf16(a_h[mt], b_l[nt], acc[mt][nt], 0, 0, 0);
                acc[mt][nt] = __builtin_amdgcn_mfma_f32_16x16x32_bf16(a_l[mt], b_h[nt], acc[mt][nt], 0, 0, 0);
            }
    }
#pragma unroll
    for (int nt = 0; nt < 2; ++nt) {
        const int f = n0 + wn + nt * 16 + lm;
        const float bf = bias[f];
#pragma unroll
        for (int mt = 0; mt < 4; ++mt)
#pragma unroll
            for (int r = 0; r < 4; ++r) {
                const int m = m0 + wm + mt * 16 + kq * 4 + r;
                C[(size_t)m * EMB + f] = acc[mt][nt][r] + bf;
            }
    }
}

// ================= Banded attention (MFMA, wave-per-16-queries) =================
// Per block (b, h, 64-query tile): 4 waves, wave wv owns queries [wv*16, wv*16+16).
// Phase 1: S[16x192] = Q·K^T via 12 n-tiles x 3 split-MFMA (hh+hl+lh), K=32=HDIM.
// Softmax fully in-register (row = quad*4+reg; col-reduce = shfl_xor 1/2/4/8).
// P -> wave-private LDS (bf16) for C-layout -> A-layout; PV: 6 k-steps x 2 n-tiles.
#define AKS 40   // Q/K row stride (u16): 80B, 16B-aligned
#define AVS 200  // Vt row stride (u16): 400B, 16B-aligned
#define APS 200  // P row stride (u16)

__global__ __launch_bounds__(256) void local_attn_kernel(
    const float* __restrict__ Qb, const float* __restrict__ Kb,
    const float* __restrict__ Vb, float* __restrict__ Ab)
{
    __shared__ __align__(16) unsigned short Qh[64 * AKS], Ql[64 * AKS];
    __shared__ __align__(16) unsigned short Kh[192 * AKS], Kl[192 * AKS];
    __shared__ __align__(16) unsigned short Vt[32 * AVS];
    __shared__ __align__(16) unsigned short Pw[4 * 16 * APS];

    const int tid = threadIdx.x;
    const int q0 = blockIdx.x * 64;
    const int h = blockIdx.y, b = blockIdx.z;
    const int jmin = max(0, q0 - WIN);
    const int jmax = min(S_LEN - 1, q0 + 63 + WIN);
    const int nk = jmax - jmin + 1;                  // <= 192
    const size_t bhS = ((size_t)b * NHEAD + h) * S_LEN;
    const float* Qg = Qb + (bhS + q0) * HDIM;        // pre-scaled by 1/sqrt(D)
    const float* Kg = Kb + (bhS + jmin) * HDIM;
    const float* Vg = Vb + (bhS + jmin) * HDIM;

    const int r0 = tid >> 3, c4 = tid & 7;
    // stage Q split hi/lo: 64 x 32
#pragma unroll
    for (int r = 0; r < 2; ++r) {
        const int row = r0 + r * 32;
        const float4 v = *(const float4*)&Qg[row * HDIM + c4 * 4];
        split_store4(&Qh[row * AKS + c4 * 4], &Ql[row * AKS + c4 * 4], v);
    }
    // stage K split hi/lo: 192 slots (tail clamped; masked via slot<nk later)
#pragma unroll
    for (int r = 0; r < 6; ++r) {
        const int t = r0 + r * 32;
        const int tc = min(t, nk - 1);
        const float4 v = *(const float4*)&Kg[tc * HDIM + c4 * 4];
        split_store4(&Kh[t * AKS + c4 * 4], &Kl[t * AKS + c4 * 4], v);
    }
    // stage V transposed, plain bf16: Vt[dim][slot]
#pragma unroll
    for (int r = 0; r < 6; ++r) {
        const int t = r0 + r * 32;
        const int tc = min(t, nk - 1);
        const float4 v = *(const float4*)&Vg[tc * HDIM + c4 * 4];
        Vt[(c4 * 4 + 0) * AVS + t] = (unsigned short)bf16_rn(v.x);
        Vt[(c4 * 4 + 1) * AVS + t] = (unsigned short)bf16_rn(v.y);
        Vt[(c4 * 4 + 2) * AVS + t] = (unsigned short)bf16_rn(v.z);
        Vt[(c4 * 4 + 3) * AVS + t] = (unsigned short)bf16_rn(v.w);
    }
    __syncthreads();

    const int lane = tid & 63, wv = tid >> 6;
    const int lm = lane & 15, quad = lane >> 4;
    const int qbase = wv * 16;

    // A-frags (this wave's 16 queries), read once
    const short8 qh = *(const short8*)&Qh[(qbase + lm) * AKS + quad * 8];
    const short8 ql = *(const short8*)&Ql[(qbase + lm) * AKS + quad * 8];

    // phase 1: 12 n-tiles of S
    floatx4 sacc[12];
#pragma unroll
    for (int nt = 0; nt < 12; ++nt) {
        const short8 bh = *(const short8*)&Kh[(nt * 16 + lm) * AKS + quad * 8];
        const short8 bl = *(const short8*)&Kl[(nt * 16 + lm) * AKS + quad * 8];
        floatx4 a = {};
        a = __builtin_amdgcn_mfma_f32_16x16x32_bf16(qh, bh, a, 0, 0, 0);
        a = __builtin_amdgcn_mfma_f32_16x16x32_bf16(qh, bl, a, 0, 0, 0);
        a = __builtin_amdgcn_mfma_f32_16x16x32_bf16(ql, bh, a, 0, 0, 0);
        sacc[nt] = a;
    }

    // mask + softmax in-register (C layout: row=quad*4+r, col=lm)
    const int qg = q0 + qbase + quad * 4;
    float mx[4] = {-1e30f, -1e30f, -1e30f, -1e30f};
#pragma unroll
    for (int nt = 0; nt < 12; ++nt) {
        const int slot = nt * 16 + lm;
        const int keyg = jmin + slot;
#pragma unroll
        for (int r = 0; r < 4; ++r) {
            const int qr = qg + r;
            const bool valid = (slot < nk) && (keyg >= qr - WIN) && (keyg <= qr + WIN);
            const float sv = valid ? sacc[nt][r] : -1e30f;
            sacc[nt][r] = sv;
            mx[r] = fmaxf(mx[r], sv);
        }
    }
#pragma unroll
    for (int r = 0; r < 4; ++r) {
        mx[r] = fmaxf(mx[r], __shfl_xor(mx[r], 1));
        mx[r] = fmaxf(mx[r], __shfl_xor(mx[r], 2));
        mx[r] = fmaxf(mx[r], __shfl_xor(mx[r], 4));
        mx[r] = fmaxf(mx[r], __shfl_xor(mx[r], 8));
    }
    float l[4] = {0.f, 0.f, 0.f, 0.f};
    unsigned short* Pme = &Pw[wv * 16 * APS];
#pragma unroll
    for (int nt = 0; nt < 12; ++nt)
#pragma unroll
        for (int r = 0; r < 4; ++r) {
            const float p = __expf(sacc[nt][r] - mx[r]);   // masked -> 0
            l[r] += p;
            Pme[(quad * 4 + r) * APS + nt * 16 + lm] = (unsigned short)bf16_rn(p);
        }
#pragma unroll
    for (int r = 0; r < 4; ++r) {
        l[r] += __shfl_xor(l[r], 1);
        l[r] += __shfl_xor(l[r], 2);
        l[r] += __shfl_xor(l[r], 4);
        l[r] += __shfl_xor(l[r], 8);
    }
    const float rl[4] = {1.f / l[0], 1.f / l[1], 1.f / l[2], 1.f / l[3]};

    // phase 2: O[16x32] = P·V (wave-private P; compiler waits on lgkmcnt)
    floatx4 oacc[2] = {};
#pragma unroll
    for (int ks = 0; ks < 6; ++ks) {
        const short8 ap  = *(const short8*)&Pme[lm * APS + ks * 32 + quad * 8];
        const short8 bv0 = *(const short8*)&Vt[lm * AVS + ks * 32 + quad * 8];
        const short8 bv1 = *(const short8*)&Vt[(16 + lm) * AVS + ks * 32 + quad * 8];
        oacc[0] = __builtin_amdgcn_mfma_f32_16x16x32_bf16(ap, bv0, oacc[0], 0, 0, 0);
        oacc[1] = __builtin_amdgcn_mfma_f32_16x16x32_bf16(ap, bv1, oacc[1], 0, 0, 0);
    }
    // epilogue: row=quad*4+r (query), col=lm (dim within n-tile)
#pragma unroll
    for (int nt = 0; nt < 2; ++nt)
#pragma unroll
        for (int r = 0; r < 4; ++r) {
            const int qrow = qbase + quad * 4 + r;
            Ab[((size_t)b * S_LEN + q0 + qrow) * EMB + h * HDIM + nt * 16 + lm]
                = oacc[nt][r] * rl[r];
        }
}

extern "C" void kernel_launch(void* const* d_in, const int* in_sizes, int n_in,
                              void* d_out, int out_size, void* d_ws, size_t ws_size,
                              hipStream_t stream) {
    const float* x  = (const float*)d_in[0];
    const float* wi = (const float*)d_in[1];
    const float* bi = (const float*)d_in[2];
    const float* wo = (const float*)d_in[3];
    const float* bo = (const float*)d_in[4];
    float* out = (float*)d_out;

    const size_t per = (size_t)BATCH * NHEAD * S_LEN * HDIM;
    float* Qb = (float*)d_ws;
    float* Kb = Qb + per;
    float* Vb = Kb + per;
    float* Ab = Vb + per;

    qkv_proj_kernel<<<dim3(768 / 64, 8192 / 128), 256, 0, stream>>>(x, wi, bi, Qb, Kb, Vb);
    local_attn_kernel<<<dim3(S_LEN / 64, NHEAD, BATCH), 256, 0, stream>>>(Qb, Kb, Vb, Ab);
    out_proj_kernel<<<dim3(256 / 64, 8192 / 128), 256, 0, stream>>>(Ab, wo, bo, out);
}